// Round 6
// baseline (330.810 us; speedup 1.0000x reference)
//
#include <hip/hip_runtime.h>

typedef _Float16 f16;
typedef __attribute__((ext_vector_type(8))) _Float16 f16x8;
typedef __attribute__((ext_vector_type(4))) _Float16 f16x4;
typedef __attribute__((ext_vector_type(4))) float floatx4;

#define MFMA16(a, b, c) __builtin_amdgcn_mfma_f32_16x16x32_f16(a, b, c, 0, 0, 0)

#define BATCH 32
#define LQ 512
#define LK 512
#define DIM 1024

// raw barrier (no vmcnt drain) + counted vmem waits — T3/T4 pattern
#define BARRIER() __builtin_amdgcn_s_barrier()
#define CFENCE() asm volatile("" ::: "memory")
#define WAITVM(n) asm volatile("s_waitcnt vmcnt(" #n ")" ::: "memory")

// async global->LDS, 16B per lane. LDS dest must be base + lane*16 within wave.
// (round-4 lesson: never pre-swizzle the global source — breaks coalescing.)
__device__ __forceinline__ void glds16(const void* g, void* l) {
    __builtin_amdgcn_global_load_lds(
        (const __attribute__((address_space(1))) unsigned int*)g,
        (__attribute__((address_space(3))) unsigned int*)l, 16, 0, 0);
}

// ---------------------------------------------------------------------------
// K0a stage 1: partial[ec][d] = sum_{e in 64-chunk ec} W[e][d]*bias[e]
// ---------------------------------------------------------------------------
__global__ __launch_bounds__(256) void k_cvec1(const float* __restrict__ W,
                                               const float* __restrict__ bias,
                                               float* __restrict__ partial) {
    __shared__ float red[256];
    int t = threadIdx.x;
    int dd = t & 63, eg = t >> 6;
    int d = blockIdx.x * 64 + dd;
    int e0 = blockIdx.y * 64 + eg * 16;
    float s = 0.f;
#pragma unroll
    for (int i = 0; i < 16; ++i)
        s += W[(size_t)(e0 + i) * DIM + d] * bias[e0 + i];
    red[t] = s;
    __syncthreads();
    if (eg == 0)
        partial[blockIdx.y * DIM + d] =
            red[dd] + red[64 + dd] + red[128 + dd] + red[192 + dd];
}

// K0a stage 2: c[d] = sum_ec partial[ec][d]; also zeroes z (16384 floats)
// ahead of k_ytrans's atomic accumulation.
__global__ __launch_bounds__(256) void k_cvec2(const float* __restrict__ partial,
                                               float* __restrict__ c,
                                               float* __restrict__ z) {
    int d = blockIdx.x * 256 + threadIdx.x;
    float s = 0.f;
#pragma unroll
    for (int j = 0; j < 16; ++j) s += partial[j * DIM + d];
    c[d] = s;
#pragma unroll
    for (int j = 0; j < 16; ++j) z[d * 16 + j] = 0.f;
}

// ---------------------------------------------------------------------------
// K_prep (fused): one launch for the three independent input streams.
//   bid [0,8192):      X16 = fp16(ix)       (2048 elems/block)
//   bid [8192,16384):  Y16 = fp16(iother)
//   bid [16384,16640): WT[d][e] = fp16(W[e][d]) (64x64 transpose tiles)
// ---------------------------------------------------------------------------
__global__ __launch_bounds__(256) void k_prep(const float* __restrict__ ix,
                                              const float* __restrict__ io,
                                              const float* __restrict__ W,
                                              f16* __restrict__ X16,
                                              f16* __restrict__ Y16,
                                              f16* __restrict__ WT) {
    const int bid = blockIdx.x;
    const int t = threadIdx.x;
    if (bid < 16384) {
        const float* src = (bid < 8192) ? ix : io;
        f16* dst = (bid < 8192) ? X16 : Y16;
        int bb = (bid < 8192) ? bid : bid - 8192;
        size_t i = ((size_t)bb * 256 + t) * 8;
        floatx4 a = *(const floatx4*)(src + i);
        floatx4 b = *(const floatx4*)(src + i + 4);
        f16x8 o;
        o[0] = (f16)a[0]; o[1] = (f16)a[1]; o[2] = (f16)a[2]; o[3] = (f16)a[3];
        o[4] = (f16)b[0]; o[5] = (f16)b[1]; o[6] = (f16)b[2]; o[7] = (f16)b[3];
        *(f16x8*)(dst + i) = o;
        return;
    }
    // ---- W transpose+convert ----
    __shared__ __align__(16) f16 S[64][72];
    const int wtb = bid - 16384;
    const int e0 = (wtb & 15) * 64, d0 = (wtb >> 4) * 64;
    {
        int row = t >> 2, cg = (t & 3) * 16;
        const float* src = W + (size_t)(e0 + row) * DIM + d0 + cg;
#pragma unroll
        for (int h = 0; h < 4; ++h) {
            floatx4 v = *(const floatx4*)(src + h * 4);
            f16x4 o;
            o[0] = (f16)v[0]; o[1] = (f16)v[1]; o[2] = (f16)v[2]; o[3] = (f16)v[3];
            *(f16x4*)&S[row][cg + h * 4] = o;
        }
    }
    __syncthreads();
    int dd = t >> 2, ms = (t & 3) * 16;
    union { f16 h[16]; uint4 u[2]; } o;
#pragma unroll
    for (int j = 0; j < 16; ++j) o.h[j] = S[ms + j][dd];
    f16* dst = WT + (size_t)(d0 + dd) * DIM + e0 + ms;
    *(uint4*)dst = o.u[0];
    *(uint4*)(dst + 8) = o.u[1];
}

// ---------------------------------------------------------------------------
// K1: Gh = fp16(WT @ WT^T) = fp16(W^T W). 128x128 tile, BK=32, linear glds,
// counted-vmcnt 2-buf pipeline (unchanged — small kernel). grid (8,8).
// ---------------------------------------------------------------------------
__global__ __launch_bounds__(256) void k_gram16(const f16* __restrict__ WT,
                                                f16* __restrict__ Gh) {
    __shared__ __align__(16) f16 sA[2][128 * 32];
    __shared__ __align__(16) f16 sB[2][128 * 32];
    const int t = threadIdx.x;
    const int lane = t & 63, wid = t >> 6;
    const int ln15 = lane & 15, q = lane >> 4;
    const int wr = (wid >> 1) * 64, wc = (wid & 1) * 64;
    const int i0 = blockIdx.x * 128, j0 = blockIdx.y * 128;
    floatx4 acc[4][4] = {};

    const int srow = t >> 2, scol = (t & 3) * 8;
    const f16* gA = WT + (size_t)(i0 + srow) * DIM + scol;
    const f16* gB = WT + (size_t)(j0 + srow) * DIM + scol;

    auto stage = [&](int buf, int e0) {
#pragma unroll
        for (int is = 0; is < 2; ++is) {
            glds16(gA + (size_t)(is * 64) * DIM + e0,
                   (char*)&sA[buf][0] + is * 4096 + t * 16);
            glds16(gB + (size_t)(is * 64) * DIM + e0,
                   (char*)&sB[buf][0] + is * 4096 + t * 16);
        }
    };
    auto compute = [&](int buf) {
        f16x8 a[4];
#pragma unroll
        for (int mi = 0; mi < 4; ++mi)
            a[mi] = *(const f16x8*)&sA[buf][(wr + mi * 16 + ln15) * 32 + q * 8];
#pragma unroll
        for (int ni = 0; ni < 4; ++ni) {
            f16x8 bv = *(const f16x8*)&sB[buf][(wc + ni * 16 + ln15) * 32 + q * 8];
#pragma unroll
            for (int mi = 0; mi < 4; ++mi)
                acc[mi][ni] = MFMA16(a[mi], bv, acc[mi][ni]);
        }
    };

    stage(0, 0);
    stage(1, 32);
    for (int tt = 0; tt < 32; ++tt) {
        if (tt < 31) { WAITVM(4); } else { WAITVM(0); }
        BARRIER();
        CFENCE();
        __builtin_amdgcn_s_setprio(1);
        compute(tt & 1);
        __builtin_amdgcn_s_setprio(0);
        CFENCE();
        BARRIER();
        if (tt < 30) stage(tt & 1, (tt + 2) * 32);
    }

#pragma unroll
    for (int mi = 0; mi < 4; ++mi)
#pragma unroll
        for (int ni = 0; ni < 4; ++ni)
#pragma unroll
            for (int r = 0; r < 4; ++r)
                Gh[(size_t)(i0 + wr + mi * 16 + q * 4 + r) * DIM +
                   j0 + wc + ni * 16 + ln15] = (f16)acc[mi][ni][r];
}

// ---------------------------------------------------------------------------
// K2: Th = fp16(X16 @ Gh). 128x128 tile, 256 thr, BK=32, linear glds.
// 3-buffer 1-barrier counted-vmcnt: step t = {wait own tile-t loads;
// barrier (=> all waves' tile-t landed, all finished step t-1 reads);
// stage tile t+2 into buf[(t+2)%3] (the buffer read at step t-1);
// compute buf[t%3]}. Halves barrier count and overlaps stage issue w/ MFMA.
// LDS 48KB -> 3 blocks/CU cap (measured occupancy was ~2.5 anyway).
// ---------------------------------------------------------------------------
__global__ __launch_bounds__(256) void k_tgemm(const f16* __restrict__ X16,
                                               const f16* __restrict__ Gh,
                                               f16* __restrict__ Th) {
    __shared__ __align__(16) f16 sA[3][128 * 32];
    __shared__ __align__(16) f16 sB[3][128 * 32];
    const int t = threadIdx.x;
    const int lane = t & 63, wid = t >> 6;
    const int ln15 = lane & 15, q = lane >> 4;
    const int wr = (wid >> 1) * 64, wc = (wid & 1) * 64;
    const int m0 = blockIdx.x * 128, n0 = blockIdx.y * 128;
    floatx4 acc[4][4] = {};

    const int srow = t >> 2, scol = (t & 3) * 8;
    const f16* gA = X16 + (size_t)(m0 + srow) * DIM + scol;
    const f16* gB = Gh + (size_t)(n0 + srow) * DIM + scol;

    auto stage = [&](int buf, int e0) {  // 4 glds16 per thread per tile
#pragma unroll
        for (int is = 0; is < 2; ++is) {
            glds16(gA + (size_t)(is * 64) * DIM + e0,
                   (char*)&sA[buf][0] + is * 4096 + t * 16);
            glds16(gB + (size_t)(is * 64) * DIM + e0,
                   (char*)&sB[buf][0] + is * 4096 + t * 16);
        }
    };
    auto compute = [&](int buf) {
        f16x8 a[4];
#pragma unroll
        for (int mi = 0; mi < 4; ++mi)
            a[mi] = *(const f16x8*)&sA[buf][(wr + mi * 16 + ln15) * 32 + q * 8];
#pragma unroll
        for (int ni = 0; ni < 4; ++ni) {
            f16x8 bv = *(const f16x8*)&sB[buf][(wc + ni * 16 + ln15) * 32 + q * 8];
#pragma unroll
            for (int mi = 0; mi < 4; ++mi)
                acc[mi][ni] = MFMA16(a[mi], bv, acc[mi][ni]);
        }
    };

    stage(0, 0);
    stage(1, 32);
    int cur = 0;
    for (int tt = 0; tt < 32; ++tt) {
        if (tt < 31) { WAITVM(4); } else { WAITVM(0); }  // drain tile tt only
        BARRIER();
        CFENCE();
        if (tt < 30) stage((cur + 2) % 3, (tt + 2) * 32);
        __builtin_amdgcn_s_setprio(1);
        compute(cur);
        __builtin_amdgcn_s_setprio(0);
        CFENCE();
        cur = (cur == 2) ? 0 : cur + 1;
    }

#pragma unroll
    for (int mi = 0; mi < 4; ++mi)
#pragma unroll
        for (int ni = 0; ni < 4; ++ni)
#pragma unroll
            for (int r = 0; r < 4; ++r)
                Th[(size_t)(m0 + wr + mi * 16 + q * 4 + r) * DIM +
                   n0 + wc + ni * 16 + ln15] = (f16)acc[mi][ni][r];
}

// ---------------------------------------------------------------------------
// K_yT: YT16[b][d][m] = Y16[b][m][d] + z[b*LK+m] += c[d-range].Y16 partials.
// (z accumulation fused here: this kernel already touches every Y16 element;
//  z was zeroed by k_cvec2.) grid (32,8,16), 64x64 tiles.
// ---------------------------------------------------------------------------
__global__ __launch_bounds__(256) void k_ytrans(const f16* __restrict__ Y16,
                                                const float* __restrict__ c,
                                                f16* __restrict__ YT,
                                                float* __restrict__ z) {
    __shared__ __align__(16) f16 S[64][72];
    const int b = blockIdx.x, m0 = blockIdx.y * 64, d0 = blockIdx.z * 64;
    const int t = threadIdx.x;
    {
        int row = t >> 2, cg = (t & 3) * 16;
        const f16* src = Y16 + (size_t)(b * LK + m0 + row) * DIM + d0 + cg;
        *(uint4*)&S[row][cg] = *(const uint4*)src;
        *(uint4*)&S[row][cg + 8] = *(const uint4*)(src + 8);
    }
    __syncthreads();
    {
        int dd = t >> 2, ms = (t & 3) * 16;
        union { f16 h[16]; uint4 u[2]; } o;
#pragma unroll
        for (int j = 0; j < 16; ++j) o.h[j] = S[ms + j][dd];
        f16* dst = YT + (size_t)(b * DIM + d0 + dd) * LK + m0 + ms;
        *(uint4*)dst = o.u[0];
        *(uint4*)(dst + 8) = o.u[1];
    }
    // ---- z partials: row = t>>2 (4 lanes/row, 16 d each) ----
    {
        int row = t >> 2, seg = (t & 3) * 16;
        float p = 0.f;
#pragma unroll
        for (int j = 0; j < 16; ++j)
            p += (float)S[row][seg + j] * c[d0 + seg + j];
        p += __shfl_xor(p, 1, 64);
        p += __shfl_xor(p, 2, 64);
        if ((t & 3) == 0) atomicAdd(&z[b * LK + m0 + row], p);
    }
}

// ---------------------------------------------------------------------------
// K3: per (b, 64 q-rows): s = Th . Y16^T + z, softmax over 512 keys,
// write unnormalized P fp16 + row sums. 512 thr (8 waves), grid 256 (1D).
// XCD batch-affinity (linear%8 == b%8). 3-buffer 1-barrier counted-vmcnt
// (same scheme as k_tgemm; waves 0-3 issue 5 glds/tile -> WAITVM(5), others
// WAITVM(4)). LDS 3x36KB, 1 block/CU.
// ---------------------------------------------------------------------------
__global__ __launch_bounds__(512) void k_attn(const f16* __restrict__ Th,
                                              const f16* __restrict__ Y16,
                                              const float* __restrict__ Z,
                                              f16* __restrict__ P,
                                              float* __restrict__ Lsum) {
    __shared__ __align__(16) f16 sS[3][18432];  // 3 x 36864 B
    __shared__ float redmax[64][8];
    __shared__ float redsum[64][8];
    const int g = blockIdx.x;
    const int b = (g & 7) + 8 * (g >> 6);        // XCD-affine batch decode
    const int l0 = ((g >> 3) & 7) * 64;
    const int t = threadIdx.x;
    const int lane = t & 63, w = t >> 6;
    const int ln15 = lane & 15, q = lane >> 4;
    const bool heavy = (t < 256);  // waves 0-3 issue 5 glds/tile
    floatx4 acc[4][4] = {};

    auto stage = [&](int buf, int e0) {
#pragma unroll
        for (int is = 0; is < 4; ++is) {
            int ff = is * 8192 + t * 16;
            const f16* g2;
            if (ff < 4096) {  // wave-uniform (boundary at t=256)
                g2 = Th + (size_t)(b * LQ + l0 + (ff >> 6)) * DIM + e0 + ((ff & 63) >> 1);
            } else {
                int f2 = ff - 4096;
                g2 = Y16 + (size_t)(b * LK + (f2 >> 6)) * DIM + e0 + ((f2 & 63) >> 1);
            }
            glds16(g2, (char*)&sS[buf][0] + ff);
        }
        if (heavy) {  // last 4KB chunk
            int ff = 32768 + t * 16;
            int f2 = ff - 4096;
            const f16* g2 = Y16 + (size_t)(b * LK + (f2 >> 6)) * DIM + e0 + ((f2 & 63) >> 1);
            glds16(g2, (char*)&sS[buf][0] + ff);
        }
    };
    auto compute = [&](int buf) {
        f16x8 th[4];
#pragma unroll
        for (int mi = 0; mi < 4; ++mi)
            th[mi] = *(const f16x8*)&sS[buf][(mi * 16 + ln15) * 32 + q * 8];
#pragma unroll
        for (int ni = 0; ni < 4; ++ni) {
            f16x8 y = *(const f16x8*)&sS[buf][2048 + (w * 64 + ni * 16 + ln15) * 32 + q * 8];
#pragma unroll
            for (int mi = 0; mi < 4; ++mi)
                acc[mi][ni] = MFMA16(th[mi], y, acc[mi][ni]);
        }
    };

    stage(0, 0);
    stage(1, 32);
    int cur = 0;
    for (int tt = 0; tt < 32; ++tt) {
        if (tt < 31) {
            if (heavy) { WAITVM(5); } else { WAITVM(4); }  // drain tile tt
        } else {
            WAITVM(0);
        }
        BARRIER();
        CFENCE();
        if (tt < 30) stage((cur + 2) % 3, (tt + 2) * 32);
        __builtin_amdgcn_s_setprio(1);
        compute(cur);
        __builtin_amdgcn_s_setprio(0);
        CFENCE();
        cur = (cur == 2) ? 0 : cur + 1;
    }

    // ---- softmax over 512 cols (8 waves x 64 cols) ----
    float zv[4];
#pragma unroll
    for (int ni = 0; ni < 4; ++ni) zv[ni] = Z[b * LK + w * 64 + ni * 16 + ln15];

    float rmx[4][4];
#pragma unroll
    for (int mi = 0; mi < 4; ++mi)
#pragma unroll
        for (int r = 0; r < 4; ++r) {
            float m = -3.0e38f;
#pragma unroll
            for (int ni = 0; ni < 4; ++ni) m = fmaxf(m, acc[mi][ni][r] + zv[ni]);
#pragma unroll
            for (int off = 1; off < 16; off <<= 1) m = fmaxf(m, __shfl_xor(m, off, 64));
            rmx[mi][r] = m;
        }
    if (ln15 == 0) {
#pragma unroll
        for (int mi = 0; mi < 4; ++mi)
#pragma unroll
            for (int r = 0; r < 4; ++r) redmax[mi * 16 + q * 4 + r][w] = rmx[mi][r];
    }
    __syncthreads();
#pragma unroll
    for (int mi = 0; mi < 4; ++mi)
#pragma unroll
        for (int r = 0; r < 4; ++r) {
            int row = mi * 16 + q * 4 + r;
            float m = redmax[row][0];
#pragma unroll
            for (int j = 1; j < 8; ++j) m = fmaxf(m, redmax[row][j]);
            rmx[mi][r] = m;
        }
    float rsm[4][4] = {};
#pragma unroll
    for (int mi = 0; mi < 4; ++mi)
#pragma unroll
        for (int ni = 0; ni < 4; ++ni)
#pragma unroll
            for (int r = 0; r < 4; ++r) {
                float e = __expf(acc[mi][ni][r] + zv[ni] - rmx[mi][r]);
                acc[mi][ni][r] = e;
                rsm[mi][r] += e;
            }
#pragma unroll
    for (int mi = 0; mi < 4; ++mi)
#pragma unroll
        for (int r = 0; r < 4; ++r) {
            float s = rsm[mi][r];
#pragma unroll
            for (int off = 1; off < 16; off <<= 1) s += __shfl_xor(s, off, 64);
            rsm[mi][r] = s;
        }
    if (ln15 == 0) {
#pragma unroll
        for (int mi = 0; mi < 4; ++mi)
#pragma unroll
            for (int r = 0; r < 4; ++r) redsum[mi * 16 + q * 4 + r][w] = rsm[mi][r];
    }
    __syncthreads();
    if (w == 0 && ln15 == 0) {
#pragma unroll
        for (int mi = 0; mi < 4; ++mi)
#pragma unroll
            for (int r = 0; r < 4; ++r) {
                int row = mi * 16 + q * 4 + r;
                float s = 0.f;
#pragma unroll
                for (int j = 0; j < 8; ++j) s += redsum[row][j];
                Lsum[b * LQ + l0 + row] = s;
            }
    }
#pragma unroll
    for (int mi = 0; mi < 4; ++mi)
#pragma unroll
        for (int ni = 0; ni < 4; ++ni)
#pragma unroll
            for (int r = 0; r < 4; ++r) {
                int row = l0 + mi * 16 + q * 4 + r;
                int col = w * 64 + ni * 16 + ln15;
                P[(size_t)(b * LQ + row) * LK + col] = (f16)acc[mi][ni][r];
            }
}

// ---------------------------------------------------------------------------
// K4: O = (P @ y) / Lsum via YT16. 128x128 tile, 256 thr, BK=32, linear
// glds, 3-buffer 1-barrier counted-vmcnt, grid 1024 (1D) with XCD
// batch-affinity. LDS 48KB.
// ---------------------------------------------------------------------------
__global__ __launch_bounds__(256) void k_pv(const f16* __restrict__ P,
                                            const f16* __restrict__ YT,
                                            const float* __restrict__ Lsum,
                                            float* __restrict__ O) {
    __shared__ __align__(16) f16 sA[3][128 * 32];
    __shared__ __align__(16) f16 sB[3][128 * 32];
    const int t = threadIdx.x;
    const int lane = t & 63, wid = t >> 6;
    const int ln15 = lane & 15, q = lane >> 4;
    const int wr = (wid >> 1) * 64, wc = (wid & 1) * 64;
    const int g = blockIdx.x;
    const int b = (g & 7) + 8 * (g >> 8);        // XCD-affine batch decode
    const int inner = (g >> 3) & 31;
    const int m0 = (inner >> 3) * 128, n0 = (inner & 7) * 128;
    floatx4 acc[4][4] = {};

    const int srow = t >> 2, scol = (t & 3) * 8;
    const f16* gA = P + (size_t)(b * LQ + m0 + srow) * LK + scol;
    const f16* gB = YT + (size_t)(b * DIM + n0 + srow) * LK + scol;

    auto stage = [&](int buf, int k0) {  // 4 glds16 per thread per tile
#pragma unroll
        for (int is = 0; is < 2; ++is) {
            glds16(gA + (size_t)(is * 64) * LK + k0,
                   (char*)&sA[buf][0] + is * 4096 + t * 16);
            glds16(gB + (size_t)(is * 64) * LK + k0,
                   (char*)&sB[buf][0] + is * 4096 + t * 16);
        }
    };
    auto compute = [&](int buf) {
        f16x8 a[4];
#pragma unroll
        for (int mi = 0; mi < 4; ++mi)
            a[mi] = *(const f16x8*)&sA[buf][(wr + mi * 16 + ln15) * 32 + q * 8];
#pragma unroll
        for (int ni = 0; ni < 4; ++ni) {
            f16x8 bv = *(const f16x8*)&sB[buf][(wc + ni * 16 + ln15) * 32 + q * 8];
#pragma unroll
            for (int mi = 0; mi < 4; ++mi) acc[mi][ni] = MFMA16(a[mi], bv, acc[mi][ni]);
        }
    };

    stage(0, 0);
    stage(1, 32);
    int cur = 0;
    for (int tt = 0; tt < 16; ++tt) {
        if (tt < 15) { WAITVM(4); } else { WAITVM(0); }
        BARRIER();
        CFENCE();
        if (tt < 14) stage((cur + 2) % 3, (tt + 2) * 32);
        __builtin_amdgcn_s_setprio(1);
        compute(cur);
        __builtin_amdgcn_s_setprio(0);
        CFENCE();
        cur = (cur == 2) ? 0 : cur + 1;
    }

    float invl[4][4];
#pragma unroll
    for (int mi = 0; mi < 4; ++mi)
#pragma unroll
        for (int r = 0; r < 4; ++r)
            invl[mi][r] = 1.0f / Lsum[b * LQ + m0 + wr + mi * 16 + q * 4 + r];
#pragma unroll
    for (int mi = 0; mi < 4; ++mi)
#pragma unroll
        for (int ni = 0; ni < 4; ++ni)
#pragma unroll
            for (int r = 0; r < 4; ++r)
                O[(size_t)(b * LQ + m0 + wr + mi * 16 + q * 4 + r) * DIM +
                  n0 + wc + ni * 16 + ln15] = acc[mi][ni][r] * invl[mi][r];
}

// ---------------------------------------------------------------------------
// Workspace layout (bytes), total ~86 MiB:
//   A:  0         X16 fp16 [16384][1024] (33,554,432); reused as YT16 after tgemm
//   B:  33554432  Y16 fp16 [32][512][1024] (33,554,432)
//   P:  67108864  P fp16 [32][512][512]    (16,777,216)
//       (head of P region doubles as WT16 fp16 [1024][1024] (2MB) before k_attn)
//   Gh: 83886080  (2,097,152)
//   c:  85983232 (4096)  z: 85987328 (65536)  L: 86052864 (65536)
//   partial: 86118400 (65536)
// d_out doubles as Th fp16 scratch (32 MB) between k_tgemm and k_attn;
// k_pv overwrites it with the final fp32 result.
// ---------------------------------------------------------------------------
extern "C" void kernel_launch(void* const* d_in, const int* in_sizes, int n_in,
                              void* d_out, int out_size, void* d_ws, size_t ws_size,
                              hipStream_t stream) {
    const float* ix = (const float*)d_in[0];
    const float* io = (const float*)d_in[1];
    const float* W = (const float*)d_in[2];
    const float* bb = (const float*)d_in[3];
    float* out = (float*)d_out;
    char* ws = (char*)d_ws;

    f16* X16 = (f16*)(ws);
    f16* YT16 = (f16*)(ws);  // same region, used after k_tgemm
    f16* Y16 = (f16*)(ws + 33554432);
    f16* P = (f16*)(ws + 67108864);
    f16* WT = (f16*)(ws + 67108864);  // overlays P region; dead before k_attn
    f16* Gh = (f16*)(ws + 83886080);
    float* c = (float*)(ws + 85983232);
    float* z = (float*)(ws + 85987328);
    float* L = (float*)(ws + 86052864);
    float* partial = (float*)(ws + 86118400);

    f16* Th = (f16*)d_out;

    k_cvec1<<<dim3(16, 16), dim3(256), 0, stream>>>(W, bb, partial);
    k_cvec2<<<dim3(4), dim3(256), 0, stream>>>(partial, c, z);
    k_prep<<<dim3(16640), dim3(256), 0, stream>>>(ix, io, W, X16, Y16, WT);
    k_gram16<<<dim3(8, 8), dim3(256), 0, stream>>>(WT, Gh);
    k_tgemm<<<dim3(128, 8), dim3(256), 0, stream>>>(X16, Gh, Th);
    k_ytrans<<<dim3(32, 8, 16), dim3(256), 0, stream>>>(Y16, c, YT16, z);
    k_attn<<<dim3(256), dim3(512), 0, stream>>>(Th, Y16, z, P, L);
    k_pv<<<dim3(1024), dim3(256), 0, stream>>>(P, YT16, L, out);
}

// Round 7
// 321.795 us; speedup vs baseline: 1.0280x; 1.0280x over previous
//
#include <hip/hip_runtime.h>

typedef _Float16 f16;
typedef __attribute__((ext_vector_type(8))) _Float16 f16x8;
typedef __attribute__((ext_vector_type(4))) _Float16 f16x4;
typedef __attribute__((ext_vector_type(4))) float floatx4;

#define MFMA16(a, b, c) __builtin_amdgcn_mfma_f32_16x16x32_f16(a, b, c, 0, 0, 0)

#define BATCH 32
#define LQ 512
#define LK 512
#define DIM 1024

// raw barrier (no vmcnt drain) + counted vmem waits — T3/T4 pattern
#define BARRIER() __builtin_amdgcn_s_barrier()
#define CFENCE() asm volatile("" ::: "memory")
#define WAITVM(n) asm volatile("s_waitcnt vmcnt(" #n ")" ::: "memory")

// async global->LDS, 16B per lane. LDS dest must be base + lane*16 within wave.
// Lessons encoded: r4 — never pre-swizzle the global source (breaks
// coalescing, FETCH +66%); r3/r6 — never grow LDS past 32KB on the 128^2
// GEMMs (co-residency 4->3 blocks/CU raises L2 misses, FETCH +56%).
__device__ __forceinline__ void glds16(const void* g, void* l) {
    __builtin_amdgcn_global_load_lds(
        (const __attribute__((address_space(1))) unsigned int*)g,
        (__attribute__((address_space(3))) unsigned int*)l, 16, 0, 0);
}

// ---------------------------------------------------------------------------
// K_prep (fused, one launch, 16904 blocks):
//   bid [0,8192):       X16 = fp16(ix)
//   bid [8192,16384):   Y16 = fp16(iother)
//   bid [16384,16640):  WT[d][e] = fp16(W[e][d])  (64x64 transpose tiles)
//   bid [16640,16896):  partial[ec][d] = sum_{e in chunk ec} W[e][d]*bias[e]
//   bid [16896,16904):  z = 0  (ahead of k_ytrans atomics)
// ---------------------------------------------------------------------------
__global__ __launch_bounds__(256) void k_prep(const float* __restrict__ ix,
                                              const float* __restrict__ io,
                                              const float* __restrict__ W,
                                              const float* __restrict__ bias,
                                              f16* __restrict__ X16,
                                              f16* __restrict__ Y16,
                                              f16* __restrict__ WT,
                                              float* __restrict__ partial,
                                              float* __restrict__ z) {
    __shared__ __align__(16) f16 S[64][72];
    const int bid = blockIdx.x;
    const int t = threadIdx.x;
    if (bid < 16384) {
        const float* src = (bid < 8192) ? ix : io;
        f16* dst = (bid < 8192) ? X16 : Y16;
        int bb = (bid < 8192) ? bid : bid - 8192;
        size_t i = ((size_t)bb * 256 + t) * 8;
        floatx4 a = *(const floatx4*)(src + i);
        floatx4 b = *(const floatx4*)(src + i + 4);
        f16x8 o;
        o[0] = (f16)a[0]; o[1] = (f16)a[1]; o[2] = (f16)a[2]; o[3] = (f16)a[3];
        o[4] = (f16)b[0]; o[5] = (f16)b[1]; o[6] = (f16)b[2]; o[7] = (f16)b[3];
        *(f16x8*)(dst + i) = o;
        return;
    }
    if (bid < 16640) {  // ---- W transpose+convert ----
        const int wtb = bid - 16384;
        const int e0 = (wtb & 15) * 64, d0 = (wtb >> 4) * 64;
        {
            int row = t >> 2, cg = (t & 3) * 16;
            const float* src = W + (size_t)(e0 + row) * DIM + d0 + cg;
#pragma unroll
            for (int h = 0; h < 4; ++h) {
                floatx4 v = *(const floatx4*)(src + h * 4);
                f16x4 o;
                o[0] = (f16)v[0]; o[1] = (f16)v[1]; o[2] = (f16)v[2]; o[3] = (f16)v[3];
                *(f16x4*)&S[row][cg + h * 4] = o;
            }
        }
        __syncthreads();
        int dd = t >> 2, ms = (t & 3) * 16;
        union { f16 h[16]; uint4 u[2]; } o;
#pragma unroll
        for (int j = 0; j < 16; ++j) o.h[j] = S[ms + j][dd];
        f16* dst = WT + (size_t)(d0 + dd) * DIM + e0 + ms;
        *(uint4*)dst = o.u[0];
        *(uint4*)(dst + 8) = o.u[1];
        return;
    }
    if (bid < 16896) {  // ---- bias-projection partials (ex-cvec1) ----
        float* red = (float*)&S[0][0];  // reuse LDS
        const int idx = bid - 16640;
        int dd = t & 63, eg = t >> 6;
        int d = (idx & 15) * 64 + dd;
        int e0 = (idx >> 4) * 64 + eg * 16;
        float s = 0.f;
#pragma unroll
        for (int i = 0; i < 16; ++i)
            s += W[(size_t)(e0 + i) * DIM + d] * bias[e0 + i];
        red[t] = s;
        __syncthreads();
        if (eg == 0)
            partial[(idx >> 4) * DIM + d] =
                red[dd] + red[64 + dd] + red[128 + dd] + red[192 + dd];
        return;
    }
    // ---- zero z ----
    int i = (bid - 16896) * 2048 + t * 8;
    floatx4 zz = {0.f, 0.f, 0.f, 0.f};
    *(floatx4*)(z + i) = zz;
    *(floatx4*)(z + i + 4) = zz;
}

// ---------------------------------------------------------------------------
// K1: Gh = fp16(WT @ WT^T) = fp16(W^T W). 128x128 tile, BK=32, linear glds,
// counted-vmcnt 2-buf pipeline. grid (8,8), 256 thr.
// Block (0,0) additionally finalizes c[d] = sum_ec partial[ec][d] (ex-cvec2;
// consumed by k_ytrans in a later launch — kernel boundary orders it).
// ---------------------------------------------------------------------------
__global__ __launch_bounds__(256) void k_gram16(const f16* __restrict__ WT,
                                                const float* __restrict__ partial,
                                                float* __restrict__ c,
                                                f16* __restrict__ Gh) {
    __shared__ __align__(16) f16 sA[2][128 * 32];
    __shared__ __align__(16) f16 sB[2][128 * 32];
    const int t = threadIdx.x;
    if (blockIdx.x == 0 && blockIdx.y == 0) {
#pragma unroll
        for (int j = 0; j < 4; ++j) {
            int d = j * 256 + t;
            float s = 0.f;
#pragma unroll
            for (int k = 0; k < 16; ++k) s += partial[k * DIM + d];
            c[d] = s;
        }
    }
    const int lane = t & 63, wid = t >> 6;
    const int ln15 = lane & 15, q = lane >> 4;
    const int wr = (wid >> 1) * 64, wc = (wid & 1) * 64;
    const int i0 = blockIdx.x * 128, j0 = blockIdx.y * 128;
    floatx4 acc[4][4] = {};

    const int srow = t >> 2, scol = (t & 3) * 8;
    const f16* gA = WT + (size_t)(i0 + srow) * DIM + scol;
    const f16* gB = WT + (size_t)(j0 + srow) * DIM + scol;

    auto stage = [&](int buf, int e0) {
#pragma unroll
        for (int is = 0; is < 2; ++is) {
            glds16(gA + (size_t)(is * 64) * DIM + e0,
                   (char*)&sA[buf][0] + is * 4096 + t * 16);
            glds16(gB + (size_t)(is * 64) * DIM + e0,
                   (char*)&sB[buf][0] + is * 4096 + t * 16);
        }
    };
    auto compute = [&](int buf) {
        f16x8 a[4];
#pragma unroll
        for (int mi = 0; mi < 4; ++mi)
            a[mi] = *(const f16x8*)&sA[buf][(wr + mi * 16 + ln15) * 32 + q * 8];
#pragma unroll
        for (int ni = 0; ni < 4; ++ni) {
            f16x8 bv = *(const f16x8*)&sB[buf][(wc + ni * 16 + ln15) * 32 + q * 8];
#pragma unroll
            for (int mi = 0; mi < 4; ++mi)
                acc[mi][ni] = MFMA16(a[mi], bv, acc[mi][ni]);
        }
    };

    stage(0, 0);
    stage(1, 32);
    for (int tt = 0; tt < 32; ++tt) {
        if (tt < 31) { WAITVM(4); } else { WAITVM(0); }
        BARRIER();
        CFENCE();
        __builtin_amdgcn_s_setprio(1);
        compute(tt & 1);
        __builtin_amdgcn_s_setprio(0);
        CFENCE();
        BARRIER();
        if (tt < 30) stage(tt & 1, (tt + 2) * 32);
    }

#pragma unroll
    for (int mi = 0; mi < 4; ++mi)
#pragma unroll
        for (int ni = 0; ni < 4; ++ni)
#pragma unroll
            for (int r = 0; r < 4; ++r)
                Gh[(size_t)(i0 + wr + mi * 16 + q * 4 + r) * DIM +
                   j0 + wc + ni * 16 + ln15] = (f16)acc[mi][ni][r];
}

// ---------------------------------------------------------------------------
// K2: Th = fp16(X16 @ Gh). EXACT round-2 config (measured 48.2-48.6 us,
// FETCH 25MB, MfmaUtil 30): 128x128 tile, 256 thr, BK=32, 2-buf 32KB LDS
// (4 blocks/CU co-residency = the L2 locality), 2-barrier counted-vmcnt.
// ---------------------------------------------------------------------------
__global__ __launch_bounds__(256) void k_tgemm(const f16* __restrict__ X16,
                                               const f16* __restrict__ Gh,
                                               f16* __restrict__ Th) {
    __shared__ __align__(16) f16 sA[2][128 * 32];
    __shared__ __align__(16) f16 sB[2][128 * 32];
    const int t = threadIdx.x;
    const int lane = t & 63, wid = t >> 6;
    const int ln15 = lane & 15, q = lane >> 4;
    const int wr = (wid >> 1) * 64, wc = (wid & 1) * 64;
    const int m0 = blockIdx.x * 128, n0 = blockIdx.y * 128;
    floatx4 acc[4][4] = {};

    const int srow = t >> 2, scol = (t & 3) * 8;
    const f16* gA = X16 + (size_t)(m0 + srow) * DIM + scol;
    const f16* gB = Gh + (size_t)(n0 + srow) * DIM + scol;

    auto stage = [&](int buf, int e0) {  // 4 glds16 per thread per tile
#pragma unroll
        for (int is = 0; is < 2; ++is) {
            glds16(gA + (size_t)(is * 64) * DIM + e0,
                   (char*)&sA[buf][0] + is * 4096 + t * 16);
            glds16(gB + (size_t)(is * 64) * DIM + e0,
                   (char*)&sB[buf][0] + is * 4096 + t * 16);
        }
    };
    auto compute = [&](int buf) {
        f16x8 a[4];
#pragma unroll
        for (int mi = 0; mi < 4; ++mi)
            a[mi] = *(const f16x8*)&sA[buf][(wr + mi * 16 + ln15) * 32 + q * 8];
#pragma unroll
        for (int ni = 0; ni < 4; ++ni) {
            f16x8 bv = *(const f16x8*)&sB[buf][(wc + ni * 16 + ln15) * 32 + q * 8];
#pragma unroll
            for (int mi = 0; mi < 4; ++mi)
                acc[mi][ni] = MFMA16(a[mi], bv, acc[mi][ni]);
        }
    };

    stage(0, 0);
    stage(1, 32);
    for (int tt = 0; tt < 32; ++tt) {
        if (tt < 31) { WAITVM(4); } else { WAITVM(0); }
        BARRIER();
        CFENCE();
        __builtin_amdgcn_s_setprio(1);
        compute(tt & 1);
        __builtin_amdgcn_s_setprio(0);
        CFENCE();
        BARRIER();
        if (tt < 30) stage(tt & 1, (tt + 2) * 32);
    }

#pragma unroll
    for (int mi = 0; mi < 4; ++mi)
#pragma unroll
        for (int ni = 0; ni < 4; ++ni)
#pragma unroll
            for (int r = 0; r < 4; ++r)
                Th[(size_t)(m0 + wr + mi * 16 + q * 4 + r) * DIM +
                   n0 + wc + ni * 16 + ln15] = (f16)acc[mi][ni][r];
}

// ---------------------------------------------------------------------------
// K_yT: YT16[b][d][m] = Y16[b][m][d], plus z[b*LK+m] += c . Y16[b][m][:]
// partials (z zeroed by k_prep; c finalized by k_gram16). grid (32,8,16).
// ---------------------------------------------------------------------------
__global__ __launch_bounds__(256) void k_ytrans(const f16* __restrict__ Y16,
                                                const float* __restrict__ c,
                                                f16* __restrict__ YT,
                                                float* __restrict__ z) {
    __shared__ __align__(16) f16 S[64][72];
    const int b = blockIdx.x, m0 = blockIdx.y * 64, d0 = blockIdx.z * 64;
    const int t = threadIdx.x;
    {
        int row = t >> 2, cg = (t & 3) * 16;
        const f16* src = Y16 + (size_t)(b * LK + m0 + row) * DIM + d0 + cg;
        *(uint4*)&S[row][cg] = *(const uint4*)src;
        *(uint4*)&S[row][cg + 8] = *(const uint4*)(src + 8);
    }
    __syncthreads();
    {
        int dd = t >> 2, ms = (t & 3) * 16;
        union { f16 h[16]; uint4 u[2]; } o;
#pragma unroll
        for (int j = 0; j < 16; ++j) o.h[j] = S[ms + j][dd];
        f16* dst = YT + (size_t)(b * DIM + d0 + dd) * LK + m0 + ms;
        *(uint4*)dst = o.u[0];
        *(uint4*)(dst + 8) = o.u[1];
    }
    // ---- z partials: row = t>>2 (4 lanes/row, 16 d each) ----
    {
        int row = t >> 2, seg = (t & 3) * 16;
        float p = 0.f;
#pragma unroll
        for (int j = 0; j < 16; ++j)
            p += (float)S[row][seg + j] * c[d0 + seg + j];
        p += __shfl_xor(p, 1, 64);
        p += __shfl_xor(p, 2, 64);
        if ((t & 3) == 0) atomicAdd(&z[b * LK + m0 + row], p);
    }
}

// ---------------------------------------------------------------------------
// K3: per (b, 64 q-rows): s = Th . Y16^T + z, softmax over 512 keys,
// write unnormalized P fp16 + row sums. 512 thr (8 waves), grid 256 (1D).
// XCD batch-affinity (linear%8 == b%8). 3-buffer 1-barrier counted-vmcnt
// (1 block/CU — LDS growth costs nothing here, unlike tgemm). r6 form.
// ---------------------------------------------------------------------------
__global__ __launch_bounds__(512) void k_attn(const f16* __restrict__ Th,
                                              const f16* __restrict__ Y16,
                                              const float* __restrict__ Z,
                                              f16* __restrict__ P,
                                              float* __restrict__ Lsum) {
    __shared__ __align__(16) f16 sS[3][18432];  // 3 x 36864 B
    __shared__ float redmax[64][8];
    __shared__ float redsum[64][8];
    const int g = blockIdx.x;
    const int b = (g & 7) + 8 * (g >> 6);        // XCD-affine batch decode
    const int l0 = ((g >> 3) & 7) * 64;
    const int t = threadIdx.x;
    const int lane = t & 63, w = t >> 6;
    const int ln15 = lane & 15, q = lane >> 4;
    const bool heavy = (t < 256);  // waves 0-3 issue 5 glds/tile
    floatx4 acc[4][4] = {};

    auto stage = [&](int buf, int e0) {
#pragma unroll
        for (int is = 0; is < 4; ++is) {
            int ff = is * 8192 + t * 16;
            const f16* g2;
            if (ff < 4096) {  // wave-uniform (boundary at t=256)
                g2 = Th + (size_t)(b * LQ + l0 + (ff >> 6)) * DIM + e0 + ((ff & 63) >> 1);
            } else {
                int f2 = ff - 4096;
                g2 = Y16 + (size_t)(b * LK + (f2 >> 6)) * DIM + e0 + ((f2 & 63) >> 1);
            }
            glds16(g2, (char*)&sS[buf][0] + ff);
        }
        if (heavy) {  // last 4KB chunk
            int ff = 32768 + t * 16;
            int f2 = ff - 4096;
            const f16* g2 = Y16 + (size_t)(b * LK + (f2 >> 6)) * DIM + e0 + ((f2 & 63) >> 1);
            glds16(g2, (char*)&sS[buf][0] + ff);
        }
    };
    auto compute = [&](int buf) {
        f16x8 th[4];
#pragma unroll
        for (int mi = 0; mi < 4; ++mi)
            th[mi] = *(const f16x8*)&sS[buf][(mi * 16 + ln15) * 32 + q * 8];
#pragma unroll
        for (int ni = 0; ni < 4; ++ni) {
            f16x8 y = *(const f16x8*)&sS[buf][2048 + (w * 64 + ni * 16 + ln15) * 32 + q * 8];
#pragma unroll
            for (int mi = 0; mi < 4; ++mi)
                acc[mi][ni] = MFMA16(th[mi], y, acc[mi][ni]);
        }
    };

    stage(0, 0);
    stage(1, 32);
    int cur = 0;
    for (int tt = 0; tt < 32; ++tt) {
        if (tt < 31) {
            if (heavy) { WAITVM(5); } else { WAITVM(4); }  // drain tile tt
        } else {
            WAITVM(0);
        }
        BARRIER();
        CFENCE();
        if (tt < 30) stage((cur + 2) % 3, (tt + 2) * 32);
        __builtin_amdgcn_s_setprio(1);
        compute(cur);
        __builtin_amdgcn_s_setprio(0);
        CFENCE();
        cur = (cur == 2) ? 0 : cur + 1;
    }

    // ---- softmax over 512 cols (8 waves x 64 cols) ----
    float zv[4];
#pragma unroll
    for (int ni = 0; ni < 4; ++ni) zv[ni] = Z[b * LK + w * 64 + ni * 16 + ln15];

    float rmx[4][4];
#pragma unroll
    for (int mi = 0; mi < 4; ++mi)
#pragma unroll
        for (int r = 0; r < 4; ++r) {
            float m = -3.0e38f;
#pragma unroll
            for (int ni = 0; ni < 4; ++ni) m = fmaxf(m, acc[mi][ni][r] + zv[ni]);
#pragma unroll
            for (int off = 1; off < 16; off <<= 1) m = fmaxf(m, __shfl_xor(m, off, 64));
            rmx[mi][r] = m;
        }
    if (ln15 == 0) {
#pragma unroll
        for (int mi = 0; mi < 4; ++mi)
#pragma unroll
            for (int r = 0; r < 4; ++r) redmax[mi * 16 + q * 4 + r][w] = rmx[mi][r];
    }
    __syncthreads();
#pragma unroll
    for (int mi = 0; mi < 4; ++mi)
#pragma unroll
        for (int r = 0; r < 4; ++r) {
            int row = mi * 16 + q * 4 + r;
            float m = redmax[row][0];
#pragma unroll
            for (int j = 1; j < 8; ++j) m = fmaxf(m, redmax[row][j]);
            rmx[mi][r] = m;
        }
    float rsm[4][4] = {};
#pragma unroll
    for (int mi = 0; mi < 4; ++mi)
#pragma unroll
        for (int ni = 0; ni < 4; ++ni)
#pragma unroll
            for (int r = 0; r < 4; ++r) {
                float e = __expf(acc[mi][ni][r] + zv[ni] - rmx[mi][r]);
                acc[mi][ni][r] = e;
                rsm[mi][r] += e;
            }
#pragma unroll
    for (int mi = 0; mi < 4; ++mi)
#pragma unroll
        for (int r = 0; r < 4; ++r) {
            float s = rsm[mi][r];
#pragma unroll
            for (int off = 1; off < 16; off <<= 1) s += __shfl_xor(s, off, 64);
            rsm[mi][r] = s;
        }
    if (ln15 == 0) {
#pragma unroll
        for (int mi = 0; mi < 4; ++mi)
#pragma unroll
            for (int r = 0; r < 4; ++r) redsum[mi * 16 + q * 4 + r][w] = rsm[mi][r];
    }
    __syncthreads();
    if (w == 0 && ln15 == 0) {
#pragma unroll
        for (int mi = 0; mi < 4; ++mi)
#pragma unroll
            for (int r = 0; r < 4; ++r) {
                int row = mi * 16 + q * 4 + r;
                float s = 0.f;
#pragma unroll
                for (int j = 0; j < 8; ++j) s += redsum[row][j];
                Lsum[b * LQ + l0 + row] = s;
            }
    }
#pragma unroll
    for (int mi = 0; mi < 4; ++mi)
#pragma unroll
        for (int ni = 0; ni < 4; ++ni)
#pragma unroll
            for (int r = 0; r < 4; ++r) {
                int row = l0 + mi * 16 + q * 4 + r;
                int col = w * 64 + ni * 16 + ln15;
                P[(size_t)(b * LQ + row) * LK + col] = (f16)acc[mi][ni][r];
            }
}

// ---------------------------------------------------------------------------
// K4: O = (P @ y) / Lsum via YT16. 128x128 tile, 256 thr, BK=32, linear
// glds, 2-buf 2-barrier counted-vmcnt (32KB LDS — same co-residency logic
// as tgemm), grid 1024 (1D) with XCD batch-affinity.
// ---------------------------------------------------------------------------
__global__ __launch_bounds__(256) void k_pv(const f16* __restrict__ P,
                                            const f16* __restrict__ YT,
                                            const float* __restrict__ Lsum,
                                            float* __restrict__ O) {
    __shared__ __align__(16) f16 sA[2][128 * 32];
    __shared__ __align__(16) f16 sB[2][128 * 32];
    const int t = threadIdx.x;
    const int lane = t & 63, wid = t >> 6;
    const int ln15 = lane & 15, q = lane >> 4;
    const int wr = (wid >> 1) * 64, wc = (wid & 1) * 64;
    const int g = blockIdx.x;
    const int b = (g & 7) + 8 * (g >> 8);        // XCD-affine batch decode
    const int inner = (g >> 3) & 31;
    const int m0 = (inner >> 3) * 128, n0 = (inner & 7) * 128;
    floatx4 acc[4][4] = {};

    const int srow = t >> 2, scol = (t & 3) * 8;
    const f16* gA = P + (size_t)(b * LQ + m0 + srow) * LK + scol;
    const f16* gB = YT + (size_t)(b * DIM + n0 + srow) * LK + scol;

    auto stage = [&](int buf, int k0) {  // 4 glds16 per thread per tile
#pragma unroll
        for (int is = 0; is < 2; ++is) {
            glds16(gA + (size_t)(is * 64) * LK + k0,
                   (char*)&sA[buf][0] + is * 4096 + t * 16);
            glds16(gB + (size_t)(is * 64) * LK + k0,
                   (char*)&sB[buf][0] + is * 4096 + t * 16);
        }
    };
    auto compute = [&](int buf) {
        f16x8 a[4];
#pragma unroll
        for (int mi = 0; mi < 4; ++mi)
            a[mi] = *(const f16x8*)&sA[buf][(wr + mi * 16 + ln15) * 32 + q * 8];
#pragma unroll
        for (int ni = 0; ni < 4; ++ni) {
            f16x8 bv = *(const f16x8*)&sB[buf][(wc + ni * 16 + ln15) * 32 + q * 8];
#pragma unroll
            for (int mi = 0; mi < 4; ++mi) acc[mi][ni] = MFMA16(a[mi], bv, acc[mi][ni]);
        }
    };

    stage(0, 0);
    stage(1, 32);
    for (int tt = 0; tt < 16; ++tt) {
        if (tt < 15) { WAITVM(4); } else { WAITVM(0); }
        BARRIER();
        CFENCE();
        __builtin_amdgcn_s_setprio(1);
        compute(tt & 1);
        __builtin_amdgcn_s_setprio(0);
        CFENCE();
        BARRIER();
        if (tt < 14) stage(tt & 1, (tt + 2) * 32);
    }

    float invl[4][4];
#pragma unroll
    for (int mi = 0; mi < 4; ++mi)
#pragma unroll
        for (int r = 0; r < 4; ++r)
            invl[mi][r] = 1.0f / Lsum[b * LQ + m0 + wr + mi * 16 + q * 4 + r];
#pragma unroll
    for (int mi = 0; mi < 4; ++mi)
#pragma unroll
        for (int ni = 0; ni < 4; ++ni)
#pragma unroll
            for (int r = 0; r < 4; ++r)
                O[(size_t)(b * LQ + m0 + wr + mi * 16 + q * 4 + r) * DIM +
                  n0 + wc + ni * 16 + ln15] = acc[mi][ni][r] * invl[mi][r];
}

// ---------------------------------------------------------------------------
// Workspace layout (bytes), total ~86 MiB:
//   A:  0         X16 fp16 [16384][1024] (33,554,432); reused as YT16 after tgemm
//   B:  33554432  Y16 fp16 [32][512][1024] (33,554,432)
//   P:  67108864  P fp16 [32][512][512]    (16,777,216)
//       (head of P region doubles as WT16 fp16 [1024][1024] (2MB) before k_attn)
//   Gh: 83886080  (2,097,152)
//   c:  85983232 (4096)  z: 85987328 (65536)  L: 86052864 (65536)
//   partial: 86118400 (65536)
// d_out doubles as Th fp16 scratch (32 MB) between k_tgemm and k_attn;
// k_pv overwrites it with the final fp32 result.
// Launch chain (6): prep -> gram16 -> tgemm -> ytrans -> attn -> pv.
// ---------------------------------------------------------------------------
extern "C" void kernel_launch(void* const* d_in, const int* in_sizes, int n_in,
                              void* d_out, int out_size, void* d_ws, size_t ws_size,
                              hipStream_t stream) {
    const float* ix = (const float*)d_in[0];
    const float* io = (const float*)d_in[1];
    const float* W = (const float*)d_in[2];
    const float* bb = (const float*)d_in[3];
    float* out = (float*)d_out;
    char* ws = (char*)d_ws;

    f16* X16 = (f16*)(ws);
    f16* YT16 = (f16*)(ws);  // same region, used after k_tgemm
    f16* Y16 = (f16*)(ws + 33554432);
    f16* P = (f16*)(ws + 67108864);
    f16* WT = (f16*)(ws + 67108864);  // overlays P region; dead before k_attn
    f16* Gh = (f16*)(ws + 83886080);
    float* c = (float*)(ws + 85983232);
    float* z = (float*)(ws + 85987328);
    float* L = (float*)(ws + 86052864);
    float* partial = (float*)(ws + 86118400);

    f16* Th = (f16*)d_out;

    k_prep<<<dim3(16904), dim3(256), 0, stream>>>(ix, io, W, bb, X16, Y16, WT,
                                                  partial, z);
    k_gram16<<<dim3(8, 8), dim3(256), 0, stream>>>(WT, partial, c, Gh);
    k_tgemm<<<dim3(128, 8), dim3(256), 0, stream>>>(X16, Gh, Th);
    k_ytrans<<<dim3(32, 8, 16), dim3(256), 0, stream>>>(Y16, c, YT16, z);
    k_attn<<<dim3(256), dim3(512), 0, stream>>>(Th, Y16, z, P, L);
    k_pv<<<dim3(1024), dim3(256), 0, stream>>>(P, YT16, L, out);
}

// Round 8
// 317.668 us; speedup vs baseline: 1.0414x; 1.0130x over previous
//
#include <hip/hip_runtime.h>

typedef _Float16 f16;
typedef __attribute__((ext_vector_type(8))) _Float16 f16x8;
typedef __attribute__((ext_vector_type(4))) _Float16 f16x4;
typedef __attribute__((ext_vector_type(4))) float floatx4;

#define MFMA16(a, b, c) __builtin_amdgcn_mfma_f32_16x16x32_f16(a, b, c, 0, 0, 0)

#define BATCH 32
#define LQ 512
#define LK 512
#define DIM 1024

// raw barrier (no vmcnt drain) + counted vmem waits — T3/T4 pattern
#define BARRIER() __builtin_amdgcn_s_barrier()
#define CFENCE() asm volatile("" ::: "memory")
#define WAITVM(n) asm volatile("s_waitcnt vmcnt(" #n ")" ::: "memory")

// async global->LDS, 16B per lane. LDS dest must be base + lane*16 within wave.
// Lessons: r4 — never pre-swizzle the global source (breaks coalescing);
// r3/r6 — never grow LDS past 32KB on the 128^2 GEMMs (co-residency loss
// raises L2 misses, FETCH +56%).
__device__ __forceinline__ void glds16(const void* g, void* l) {
    __builtin_amdgcn_global_load_lds(
        (const __attribute__((address_space(1))) unsigned int*)g,
        (__attribute__((address_space(3))) unsigned int*)l, 16, 0, 0);
}

// ===========================================================================
// K_prep fused (needs big workspace: YT has its own region):
//   bid [0,2048):     X16 = fp16(ix), grid-stride x4 (ILP)
//   bid [2048,6144):  io 64x64 tiles -> Y16 (row-major) + YT (transposed)
//   bid [6144,6400):  WT[d][e] = fp16(W[e][d])
//   bid [6400,6656):  partial[ec][d] = sum_{e in chunk} W[e][d]*bias[e]
// ===========================================================================
__global__ __launch_bounds__(256) void k_prep_f(const float* __restrict__ ix,
                                                const float* __restrict__ io,
                                                const float* __restrict__ W,
                                                const float* __restrict__ bias,
                                                f16* __restrict__ X16,
                                                f16* __restrict__ Y16,
                                                f16* __restrict__ YT,
                                                f16* __restrict__ WT,
                                                float* __restrict__ partial) {
    __shared__ __align__(16) f16 S[64][72];
    const int bid = blockIdx.x;
    const int t = threadIdx.x;
    if (bid < 2048) {  // ---- X convert, 4 chunks/thread ----
#pragma unroll
        for (int k = 0; k < 4; ++k) {
            size_t i = ((size_t)bid * 1024 + k * 256 + t) * 8;
            floatx4 a = *(const floatx4*)(ix + i);
            floatx4 b = *(const floatx4*)(ix + i + 4);
            f16x8 o;
            o[0] = (f16)a[0]; o[1] = (f16)a[1]; o[2] = (f16)a[2]; o[3] = (f16)a[3];
            o[4] = (f16)b[0]; o[5] = (f16)b[1]; o[6] = (f16)b[2]; o[7] = (f16)b[3];
            *(f16x8*)(X16 + i) = o;
        }
        return;
    }
    if (bid < 6144) {  // ---- io tile: convert once -> Y16 + YT ----
        const int idx = bid - 2048;
        const int b = idx >> 7;
        const int m0 = ((idx >> 4) & 7) * 64, d0 = (idx & 15) * 64;
        {
            int row = t >> 2, cg = (t & 3) * 16;
            const float* src = io + (size_t)(b * LK + m0 + row) * DIM + d0 + cg;
            union { f16 h[16]; uint4 u[2]; } o;
#pragma unroll
            for (int h2 = 0; h2 < 4; ++h2) {
                floatx4 v = *(const floatx4*)(src + h2 * 4);
                o.h[h2 * 4 + 0] = (f16)v[0]; o.h[h2 * 4 + 1] = (f16)v[1];
                o.h[h2 * 4 + 2] = (f16)v[2]; o.h[h2 * 4 + 3] = (f16)v[3];
            }
            *(uint4*)&S[row][cg] = o.u[0];
            *(uint4*)&S[row][cg + 8] = o.u[1];
            f16* yd = Y16 + (size_t)(b * LK + m0 + row) * DIM + d0 + cg;
            *(uint4*)yd = o.u[0];
            *(uint4*)(yd + 8) = o.u[1];
        }
        __syncthreads();
        int dd = t >> 2, ms = (t & 3) * 16;
        union { f16 h[16]; uint4 u[2]; } o;
#pragma unroll
        for (int j = 0; j < 16; ++j) o.h[j] = S[ms + j][dd];
        f16* dst = YT + (size_t)(b * DIM + d0 + dd) * LK + m0 + ms;
        *(uint4*)dst = o.u[0];
        *(uint4*)(dst + 8) = o.u[1];
        return;
    }
    if (bid < 6400) {  // ---- W transpose+convert ----
        const int wtb = bid - 6144;
        const int e0 = (wtb & 15) * 64, d0 = (wtb >> 4) * 64;
        {
            int row = t >> 2, cg = (t & 3) * 16;
            const float* src = W + (size_t)(e0 + row) * DIM + d0 + cg;
#pragma unroll
            for (int h = 0; h < 4; ++h) {
                floatx4 v = *(const floatx4*)(src + h * 4);
                f16x4 o;
                o[0] = (f16)v[0]; o[1] = (f16)v[1]; o[2] = (f16)v[2]; o[3] = (f16)v[3];
                *(f16x4*)&S[row][cg + h * 4] = o;
            }
        }
        __syncthreads();
        int dd = t >> 2, ms = (t & 3) * 16;
        union { f16 h[16]; uint4 u[2]; } o;
#pragma unroll
        for (int j = 0; j < 16; ++j) o.h[j] = S[ms + j][dd];
        f16* dst = WT + (size_t)(d0 + dd) * DIM + e0 + ms;
        *(uint4*)dst = o.u[0];
        *(uint4*)(dst + 8) = o.u[1];
        return;
    }
    // ---- bias-projection partials ----
    {
        float* red = (float*)&S[0][0];
        const int idx = bid - 6400;
        int dd = t & 63, eg = t >> 6;
        int d = (idx & 15) * 64 + dd;
        int e0 = (idx >> 4) * 64 + eg * 16;
        float s = 0.f;
#pragma unroll
        for (int i = 0; i < 16; ++i)
            s += W[(size_t)(e0 + i) * DIM + d] * bias[e0 + i];
        red[t] = s;
        __syncthreads();
        if (eg == 0)
            partial[(idx >> 4) * DIM + d] =
                red[dd] + red[64 + dd] + red[128 + dd] + red[192 + dd];
    }
}

// ===========================================================================
// K_prep basic (fallback, 86MB layout — no YT here):
//   bid [0,2048): X16   [2048,4096): Y16   [4096,4352): WT  [4352,4608): partial
// ===========================================================================
__global__ __launch_bounds__(256) void k_prep_b(const float* __restrict__ ix,
                                                const float* __restrict__ io,
                                                const float* __restrict__ W,
                                                const float* __restrict__ bias,
                                                f16* __restrict__ X16,
                                                f16* __restrict__ Y16,
                                                f16* __restrict__ WT,
                                                float* __restrict__ partial) {
    __shared__ __align__(16) f16 S[64][72];
    const int bid = blockIdx.x;
    const int t = threadIdx.x;
    if (bid < 4096) {
        const float* src = (bid < 2048) ? ix : io;
        f16* dst = (bid < 2048) ? X16 : Y16;
        int bb = bid & 2047;
#pragma unroll
        for (int k = 0; k < 4; ++k) {
            size_t i = ((size_t)bb * 1024 + k * 256 + t) * 8;
            floatx4 a = *(const floatx4*)(src + i);
            floatx4 b = *(const floatx4*)(src + i + 4);
            f16x8 o;
            o[0] = (f16)a[0]; o[1] = (f16)a[1]; o[2] = (f16)a[2]; o[3] = (f16)a[3];
            o[4] = (f16)b[0]; o[5] = (f16)b[1]; o[6] = (f16)b[2]; o[7] = (f16)b[3];
            *(f16x8*)(dst + i) = o;
        }
        return;
    }
    if (bid < 4352) {
        const int wtb = bid - 4096;
        const int e0 = (wtb & 15) * 64, d0 = (wtb >> 4) * 64;
        {
            int row = t >> 2, cg = (t & 3) * 16;
            const float* src = W + (size_t)(e0 + row) * DIM + d0 + cg;
#pragma unroll
            for (int h = 0; h < 4; ++h) {
                floatx4 v = *(const floatx4*)(src + h * 4);
                f16x4 o;
                o[0] = (f16)v[0]; o[1] = (f16)v[1]; o[2] = (f16)v[2]; o[3] = (f16)v[3];
                *(f16x4*)&S[row][cg + h * 4] = o;
            }
        }
        __syncthreads();
        int dd = t >> 2, ms = (t & 3) * 16;
        union { f16 h[16]; uint4 u[2]; } o;
#pragma unroll
        for (int j = 0; j < 16; ++j) o.h[j] = S[ms + j][dd];
        f16* dst = WT + (size_t)(d0 + dd) * DIM + e0 + ms;
        *(uint4*)dst = o.u[0];
        *(uint4*)(dst + 8) = o.u[1];
        return;
    }
    {
        float* red = (float*)&S[0][0];
        const int idx = bid - 4352;
        int dd = t & 63, eg = t >> 6;
        int d = (idx & 15) * 64 + dd;
        int e0 = (idx >> 4) * 64 + eg * 16;
        float s = 0.f;
#pragma unroll
        for (int i = 0; i < 16; ++i)
            s += W[(size_t)(e0 + i) * DIM + d] * bias[e0 + i];
        red[t] = s;
        __syncthreads();
        if (eg == 0)
            partial[(idx >> 4) * DIM + d] =
                red[dd] + red[64 + dd] + red[128 + dd] + red[192 + dd];
    }
}

// K_yT (fallback only): pure transpose Y16 -> YT. grid (32,8,16).
__global__ __launch_bounds__(256) void k_ytrans(const f16* __restrict__ Y16,
                                                f16* __restrict__ YT) {
    __shared__ __align__(16) f16 S[64][72];
    const int b = blockIdx.x, m0 = blockIdx.y * 64, d0 = blockIdx.z * 64;
    const int t = threadIdx.x;
    {
        int row = t >> 2, cg = (t & 3) * 16;
        const f16* src = Y16 + (size_t)(b * LK + m0 + row) * DIM + d0 + cg;
        *(uint4*)&S[row][cg] = *(const uint4*)src;
        *(uint4*)&S[row][cg + 8] = *(const uint4*)(src + 8);
    }
    __syncthreads();
    int dd = t >> 2, ms = (t & 3) * 16;
    union { f16 h[16]; uint4 u[2]; } o;
#pragma unroll
    for (int j = 0; j < 16; ++j) o.h[j] = S[ms + j][dd];
    f16* dst = YT + (size_t)(b * DIM + d0 + dd) * LK + m0 + ms;
    *(uint4*)dst = o.u[0];
    *(uint4*)(dst + 8) = o.u[1];
}

// ===========================================================================
// K1: gram (64 blocks) + z (256 blocks) in ONE launch — gram alone leaves
// 192 CUs idle, z-blocks fill them for ~free.
//   bid < 64:  Gh = fp16(WT @ WT^T), 128x128 tile, counted-vmcnt 2-buf.
//   bid >= 64: z[row] = c . Y16[row] with c rebuilt from partial in LDS
//              (wave-per-quarter -> all LDS c-reads are lane-uniform
//              broadcasts; z written non-atomically: no zeroing, no races).
// ===========================================================================
__global__ __launch_bounds__(256) void k_gram_z(const f16* __restrict__ WT,
                                                const float* __restrict__ partial,
                                                const f16* __restrict__ Y16,
                                                f16* __restrict__ Gh,
                                                float* __restrict__ z) {
    __shared__ __align__(16) f16 sA[2][128 * 32];
    __shared__ __align__(16) f16 sB[2][128 * 32];
    __shared__ float cL[DIM];
    __shared__ float red[4][64];
    const int t = threadIdx.x;
    if (blockIdx.x >= 64) {  // ---- z block: 64 rows each ----
        const int idx = blockIdx.x - 64;
        const int lane = t & 63, w = t >> 6;
#pragma unroll
        for (int j = 0; j < 4; ++j) {
            int d = j * 256 + t;
            float s = 0.f;
#pragma unroll
            for (int k = 0; k < 16; ++k) s += partial[k * DIM + d];
            cL[d] = s;
        }
        __syncthreads();
        const int row = idx * 64 + lane;           // global (b*LK + m)
        const f16* yr = Y16 + (size_t)row * DIM + w * 256;
        float s = 0.f;
#pragma unroll
        for (int c8 = 0; c8 < 256; c8 += 8) {
            f16x8 v = *(const f16x8*)(yr + c8);
#pragma unroll
            for (int j = 0; j < 8; ++j) s += (float)v[j] * cL[w * 256 + c8 + j];
        }
        red[w][lane] = s;
        __syncthreads();
        if (w == 0)
            z[row] = red[0][lane] + red[1][lane] + red[2][lane] + red[3][lane];
        return;
    }
    // ---- gram block ----
    const int lane = t & 63, wid = t >> 6;
    const int ln15 = lane & 15, q = lane >> 4;
    const int wr = (wid >> 1) * 64, wc = (wid & 1) * 64;
    const int i0 = (blockIdx.x >> 3) * 128, j0 = (blockIdx.x & 7) * 128;
    floatx4 acc[4][4] = {};

    const int srow = t >> 2, scol = (t & 3) * 8;
    const f16* gA = WT + (size_t)(i0 + srow) * DIM + scol;
    const f16* gB = WT + (size_t)(j0 + srow) * DIM + scol;

    auto stage = [&](int buf, int e0) {
#pragma unroll
        for (int is = 0; is < 2; ++is) {
            glds16(gA + (size_t)(is * 64) * DIM + e0,
                   (char*)&sA[buf][0] + is * 4096 + t * 16);
            glds16(gB + (size_t)(is * 64) * DIM + e0,
                   (char*)&sB[buf][0] + is * 4096 + t * 16);
        }
    };
    auto compute = [&](int buf) {
        f16x8 a[4];
#pragma unroll
        for (int mi = 0; mi < 4; ++mi)
            a[mi] = *(const f16x8*)&sA[buf][(wr + mi * 16 + ln15) * 32 + q * 8];
#pragma unroll
        for (int ni = 0; ni < 4; ++ni) {
            f16x8 bv = *(const f16x8*)&sB[buf][(wc + ni * 16 + ln15) * 32 + q * 8];
#pragma unroll
            for (int mi = 0; mi < 4; ++mi)
                acc[mi][ni] = MFMA16(a[mi], bv, acc[mi][ni]);
        }
    };

    stage(0, 0);
    stage(1, 32);
    for (int tt = 0; tt < 32; ++tt) {
        if (tt < 31) { WAITVM(4); } else { WAITVM(0); }
        BARRIER();
        CFENCE();
        __builtin_amdgcn_s_setprio(1);
        compute(tt & 1);
        __builtin_amdgcn_s_setprio(0);
        CFENCE();
        BARRIER();
        if (tt < 30) stage(tt & 1, (tt + 2) * 32);
    }

#pragma unroll
    for (int mi = 0; mi < 4; ++mi)
#pragma unroll
        for (int ni = 0; ni < 4; ++ni)
#pragma unroll
            for (int r = 0; r < 4; ++r)
                Gh[(size_t)(i0 + wr + mi * 16 + q * 4 + r) * DIM +
                   j0 + wc + ni * 16 + ln15] = (f16)acc[mi][ni][r];
}

// ===========================================================================
// K2: Th = fp16(X16 @ Gh). Proven round-2 config: 128x128, 256 thr, BK=32,
// 2-buf 32KB LDS (4 blocks/CU), 2-barrier counted-vmcnt.
// ===========================================================================
__global__ __launch_bounds__(256) void k_tgemm(const f16* __restrict__ X16,
                                               const f16* __restrict__ Gh,
                                               f16* __restrict__ Th) {
    __shared__ __align__(16) f16 sA[2][128 * 32];
    __shared__ __align__(16) f16 sB[2][128 * 32];
    const int t = threadIdx.x;
    const int lane = t & 63, wid = t >> 6;
    const int ln15 = lane & 15, q = lane >> 4;
    const int wr = (wid >> 1) * 64, wc = (wid & 1) * 64;
    const int m0 = blockIdx.x * 128, n0 = blockIdx.y * 128;
    floatx4 acc[4][4] = {};

    const int srow = t >> 2, scol = (t & 3) * 8;
    const f16* gA = X16 + (size_t)(m0 + srow) * DIM + scol;
    const f16* gB = Gh + (size_t)(n0 + srow) * DIM + scol;

    auto stage = [&](int buf, int e0) {
#pragma unroll
        for (int is = 0; is < 2; ++is) {
            glds16(gA + (size_t)(is * 64) * DIM + e0,
                   (char*)&sA[buf][0] + is * 4096 + t * 16);
            glds16(gB + (size_t)(is * 64) * DIM + e0,
                   (char*)&sB[buf][0] + is * 4096 + t * 16);
        }
    };
    auto compute = [&](int buf) {
        f16x8 a[4];
#pragma unroll
        for (int mi = 0; mi < 4; ++mi)
            a[mi] = *(const f16x8*)&sA[buf][(wr + mi * 16 + ln15) * 32 + q * 8];
#pragma unroll
        for (int ni = 0; ni < 4; ++ni) {
            f16x8 bv = *(const f16x8*)&sB[buf][(wc + ni * 16 + ln15) * 32 + q * 8];
#pragma unroll
            for (int mi = 0; mi < 4; ++mi)
                acc[mi][ni] = MFMA16(a[mi], bv, acc[mi][ni]);
        }
    };

    stage(0, 0);
    stage(1, 32);
    for (int tt = 0; tt < 32; ++tt) {
        if (tt < 31) { WAITVM(4); } else { WAITVM(0); }
        BARRIER();
        CFENCE();
        __builtin_amdgcn_s_setprio(1);
        compute(tt & 1);
        __builtin_amdgcn_s_setprio(0);
        CFENCE();
        BARRIER();
        if (tt < 30) stage(tt & 1, (tt + 2) * 32);
    }

#pragma unroll
    for (int mi = 0; mi < 4; ++mi)
#pragma unroll
        for (int ni = 0; ni < 4; ++ni)
#pragma unroll
            for (int r = 0; r < 4; ++r)
                Th[(size_t)(m0 + wr + mi * 16 + q * 4 + r) * DIM +
                   n0 + wc + ni * 16 + ln15] = (f16)acc[mi][ni][r];
}

// ===========================================================================
// K3: QK^T + softmax -> P, Lsum. r7 form (XCD batch-affinity, 3-buf
// 1-barrier counted-vmcnt, 1 block/CU). grid 256, 512 thr.
// ===========================================================================
__global__ __launch_bounds__(512) void k_attn(const f16* __restrict__ Th,
                                              const f16* __restrict__ Y16,
                                              const float* __restrict__ Z,
                                              f16* __restrict__ P,
                                              float* __restrict__ Lsum) {
    __shared__ __align__(16) f16 sS[3][18432];  // 3 x 36864 B
    __shared__ float redmax[64][8];
    __shared__ float redsum[64][8];
    const int g = blockIdx.x;
    const int b = (g & 7) + 8 * (g >> 6);
    const int l0 = ((g >> 3) & 7) * 64;
    const int t = threadIdx.x;
    const int lane = t & 63, w = t >> 6;
    const int ln15 = lane & 15, q = lane >> 4;
    const bool heavy = (t < 256);
    floatx4 acc[4][4] = {};

    auto stage = [&](int buf, int e0) {
#pragma unroll
        for (int is = 0; is < 4; ++is) {
            int ff = is * 8192 + t * 16;
            const f16* g2;
            if (ff < 4096) {
                g2 = Th + (size_t)(b * LQ + l0 + (ff >> 6)) * DIM + e0 + ((ff & 63) >> 1);
            } else {
                int f2 = ff - 4096;
                g2 = Y16 + (size_t)(b * LK + (f2 >> 6)) * DIM + e0 + ((f2 & 63) >> 1);
            }
            glds16(g2, (char*)&sS[buf][0] + ff);
        }
        if (heavy) {
            int ff = 32768 + t * 16;
            int f2 = ff - 4096;
            const f16* g2 = Y16 + (size_t)(b * LK + (f2 >> 6)) * DIM + e0 + ((f2 & 63) >> 1);
            glds16(g2, (char*)&sS[buf][0] + ff);
        }
    };
    auto compute = [&](int buf) {
        f16x8 th[4];
#pragma unroll
        for (int mi = 0; mi < 4; ++mi)
            th[mi] = *(const f16x8*)&sS[buf][(mi * 16 + ln15) * 32 + q * 8];
#pragma unroll
        for (int ni = 0; ni < 4; ++ni) {
            f16x8 y = *(const f16x8*)&sS[buf][2048 + (w * 64 + ni * 16 + ln15) * 32 + q * 8];
#pragma unroll
            for (int mi = 0; mi < 4; ++mi)
                acc[mi][ni] = MFMA16(th[mi], y, acc[mi][ni]);
        }
    };

    stage(0, 0);
    stage(1, 32);
    int cur = 0;
    for (int tt = 0; tt < 32; ++tt) {
        if (tt < 31) {
            if (heavy) { WAITVM(5); } else { WAITVM(4); }
        } else {
            WAITVM(0);
        }
        BARRIER();
        CFENCE();
        if (tt < 30) stage((cur + 2) % 3, (tt + 2) * 32);
        __builtin_amdgcn_s_setprio(1);
        compute(cur);
        __builtin_amdgcn_s_setprio(0);
        CFENCE();
        cur = (cur == 2) ? 0 : cur + 1;
    }

    float zv[4];
#pragma unroll
    for (int ni = 0; ni < 4; ++ni) zv[ni] = Z[b * LK + w * 64 + ni * 16 + ln15];

    float rmx[4][4];
#pragma unroll
    for (int mi = 0; mi < 4; ++mi)
#pragma unroll
        for (int r = 0; r < 4; ++r) {
            float m = -3.0e38f;
#pragma unroll
            for (int ni = 0; ni < 4; ++ni) m = fmaxf(m, acc[mi][ni][r] + zv[ni]);
#pragma unroll
            for (int off = 1; off < 16; off <<= 1) m = fmaxf(m, __shfl_xor(m, off, 64));
            rmx[mi][r] = m;
        }
    if (ln15 == 0) {
#pragma unroll
        for (int mi = 0; mi < 4; ++mi)
#pragma unroll
            for (int r = 0; r < 4; ++r) redmax[mi * 16 + q * 4 + r][w] = rmx[mi][r];
    }
    __syncthreads();
#pragma unroll
    for (int mi = 0; mi < 4; ++mi)
#pragma unroll
        for (int r = 0; r < 4; ++r) {
            int row = mi * 16 + q * 4 + r;
            float m = redmax[row][0];
#pragma unroll
            for (int j = 1; j < 8; ++j) m = fmaxf(m, redmax[row][j]);
            rmx[mi][r] = m;
        }
    float rsm[4][4] = {};
#pragma unroll
    for (int mi = 0; mi < 4; ++mi)
#pragma unroll
        for (int ni = 0; ni < 4; ++ni)
#pragma unroll
            for (int r = 0; r < 4; ++r) {
                float e = __expf(acc[mi][ni][r] + zv[ni] - rmx[mi][r]);
                acc[mi][ni][r] = e;
                rsm[mi][r] += e;
            }
#pragma unroll
    for (int mi = 0; mi < 4; ++mi)
#pragma unroll
        for (int r = 0; r < 4; ++r) {
            float s = rsm[mi][r];
#pragma unroll
            for (int off = 1; off < 16; off <<= 1) s += __shfl_xor(s, off, 64);
            rsm[mi][r] = s;
        }
    if (ln15 == 0) {
#pragma unroll
        for (int mi = 0; mi < 4; ++mi)
#pragma unroll
            for (int r = 0; r < 4; ++r) redsum[mi * 16 + q * 4 + r][w] = rsm[mi][r];
    }
    __syncthreads();
    if (w == 0 && ln15 == 0) {
#pragma unroll
        for (int mi = 0; mi < 4; ++mi)
#pragma unroll
            for (int r = 0; r < 4; ++r) {
                int row = mi * 16 + q * 4 + r;
                float s = 0.f;
#pragma unroll
                for (int j = 0; j < 8; ++j) s += redsum[row][j];
                Lsum[b * LQ + l0 + row] = s;
            }
    }
#pragma unroll
    for (int mi = 0; mi < 4; ++mi)
#pragma unroll
        for (int ni = 0; ni < 4; ++ni)
#pragma unroll
            for (int r = 0; r < 4; ++r) {
                int row = l0 + mi * 16 + q * 4 + r;
                int col = w * 64 + ni * 16 + ln15;
                P[(size_t)(b * LQ + row) * LK + col] = (f16)acc[mi][ni][r];
            }
}

// ===========================================================================
// K4: O = (P @ y) / Lsum via YT. r7 form (2-buf 32KB, XCD batch-affinity).
// ===========================================================================
__global__ __launch_bounds__(256) void k_pv(const f16* __restrict__ P,
                                            const f16* __restrict__ YT,
                                            const float* __restrict__ Lsum,
                                            float* __restrict__ O) {
    __shared__ __align__(16) f16 sA[2][128 * 32];
    __shared__ __align__(16) f16 sB[2][128 * 32];
    const int t = threadIdx.x;
    const int lane = t & 63, wid = t >> 6;
    const int ln15 = lane & 15, q = lane >> 4;
    const int wr = (wid >> 1) * 64, wc = (wid & 1) * 64;
    const int g = blockIdx.x;
    const int b = (g & 7) + 8 * (g >> 8);
    const int inner = (g >> 3) & 31;
    const int m0 = (inner >> 3) * 128, n0 = (inner & 7) * 128;
    floatx4 acc[4][4] = {};

    const int srow = t >> 2, scol = (t & 3) * 8;
    const f16* gA = P + (size_t)(b * LQ + m0 + srow) * LK + scol;
    const f16* gB = YT + (size_t)(b * DIM + n0 + srow) * LK + scol;

    auto stage = [&](int buf, int k0) {
#pragma unroll
        for (int is = 0; is < 2; ++is) {
            glds16(gA + (size_t)(is * 64) * LK + k0,
                   (char*)&sA[buf][0] + is * 4096 + t * 16);
            glds16(gB + (size_t)(is * 64) * LK + k0,
                   (char*)&sB[buf][0] + is * 4096 + t * 16);
        }
    };
    auto compute = [&](int buf) {
        f16x8 a[4];
#pragma unroll
        for (int mi = 0; mi < 4; ++mi)
            a[mi] = *(const f16x8*)&sA[buf][(wr + mi * 16 + ln15) * 32 + q * 8];
#pragma unroll
        for (int ni = 0; ni < 4; ++ni) {
            f16x8 bv = *(const f16x8*)&sB[buf][(wc + ni * 16 + ln15) * 32 + q * 8];
#pragma unroll
            for (int mi = 0; mi < 4; ++mi) acc[mi][ni] = MFMA16(a[mi], bv, acc[mi][ni]);
        }
    };

    stage(0, 0);
    stage(1, 32);
    for (int tt = 0; tt < 16; ++tt) {
        if (tt < 15) { WAITVM(4); } else { WAITVM(0); }
        BARRIER();
        CFENCE();
        __builtin_amdgcn_s_setprio(1);
        compute(tt & 1);
        __builtin_amdgcn_s_setprio(0);
        CFENCE();
        BARRIER();
        if (tt < 14) stage(tt & 1, (tt + 2) * 32);
    }

    float invl[4][4];
#pragma unroll
    for (int mi = 0; mi < 4; ++mi)
#pragma unroll
        for (int r = 0; r < 4; ++r)
            invl[mi][r] = 1.0f / Lsum[b * LQ + m0 + wr + mi * 16 + q * 4 + r];
#pragma unroll
    for (int mi = 0; mi < 4; ++mi)
#pragma unroll
        for (int ni = 0; ni < 4; ++ni)
#pragma unroll
            for (int r = 0; r < 4; ++r)
                O[(size_t)(b * LQ + m0 + wr + mi * 16 + q * 4 + r) * DIM +
                  n0 + wc + ni * 16 + ln15] = acc[mi][ni][r] * invl[mi][r];
}

// ---------------------------------------------------------------------------
// Two workspace layouts:
// FUSED (needs ~100.2 MB): X16@0 (L1-L3, P@0 L4-L5 after it dies),
//   Y16@32M, YT@64M (own region -> prep can write it), Gh@96M, WT@98M,
//   partial/z/L tail.  5 launches: prep_f, gram_z, tgemm, attn, pv.
// BASIC (fits 86.2 MB): r7 layout — X16/YT share @0 (YT written after
//   tgemm by k_ytrans), Y16@32M, P+WT@64M, Gh@80M.  6 launches.
// ---------------------------------------------------------------------------
extern "C" void kernel_launch(void* const* d_in, const int* in_sizes, int n_in,
                              void* d_out, int out_size, void* d_ws, size_t ws_size,
                              hipStream_t stream) {
    const float* ix = (const float*)d_in[0];
    const float* io = (const float*)d_in[1];
    const float* W = (const float*)d_in[2];
    const float* bb = (const float*)d_in[3];
    float* out = (float*)d_out;
    char* ws = (char*)d_ws;
    f16* Th = (f16*)d_out;  // first 32MB of d_out, dead before k_pv writes

    if (ws_size >= 105054208ull) {  // fused layout
        f16* X16 = (f16*)(ws);
        f16* P = (f16*)(ws);                    // over dead X16 (L4+)
        f16* Y16 = (f16*)(ws + 33554432);
        f16* YT = (f16*)(ws + 67108864);
        f16* Gh = (f16*)(ws + 100663296);
        f16* WT = (f16*)(ws + 102760448);
        float* partial = (float*)(ws + 104857600);
        float* z = (float*)(ws + 104923136);
        float* L = (float*)(ws + 104988672);

        k_prep_f<<<dim3(6656), dim3(256), 0, stream>>>(ix, io, W, bb, X16, Y16,
                                                       YT, WT, partial);
        k_gram_z<<<dim3(320), dim3(256), 0, stream>>>(WT, partial, Y16, Gh, z);
        k_tgemm<<<dim3(128, 8), dim3(256), 0, stream>>>(X16, Gh, Th);
        k_attn<<<dim3(256), dim3(512), 0, stream>>>(Th, Y16, z, P, L);
        k_pv<<<dim3(1024), dim3(256), 0, stream>>>(P, YT, L, out);
    } else {  // basic (86.2 MB) layout
        f16* X16 = (f16*)(ws);
        f16* YT = (f16*)(ws);                   // written after tgemm
        f16* Y16 = (f16*)(ws + 33554432);
        f16* P = (f16*)(ws + 67108864);
        f16* WT = (f16*)(ws + 67108864);        // dead before attn writes P
        f16* Gh = (f16*)(ws + 83886080);
        float* z = (float*)(ws + 85987328);
        float* L = (float*)(ws + 86052864);
        float* partial = (float*)(ws + 86118400);

        k_prep_b<<<dim3(4608), dim3(256), 0, stream>>>(ix, io, W, bb, X16, Y16,
                                                       WT, partial);
        k_gram_z<<<dim3(320), dim3(256), 0, stream>>>(WT, partial, Y16, Gh, z);
        k_tgemm<<<dim3(128, 8), dim3(256), 0, stream>>>(X16, Gh, Th);
        k_ytrans<<<dim3(32, 8, 16), dim3(256), 0, stream>>>(Y16, YT);
        k_attn<<<dim3(256), dim3(512), 0, stream>>>(Th, Y16, z, P, L);
        k_pv<<<dim3(1024), dim3(256), 0, stream>>>(P, YT, L, out);
    }
}